// Round 5
// baseline (207.075 us; speedup 1.0000x reference)
//
#include <hip/hip_runtime.h>

// MeanConv: out = mask * (1/7) * sum_{k in 3,5,..,15} boxmean_k(x), edge padding.
// Per-tile 2D integral image in LDS; each box sum = 4-corner difference.
//   P1: stage+row-prefix fused (registers + 4-lane __shfl_up fixup).
//   P2: column prefix (register segments + 4-lane shuffle fixup).
//   P3: 8 px/thread, corner reads merge to ds_read2_b32.
// Round-5 changes (latency attack; no pipe >30% busy in round 4):
//   - mask prefetched at kernel entry -> ~900cyc HBM latency hidden behind P1/P2
//   - XCD-aware tile swizzle: each XCD gets a contiguous 8-tile-row strip so
//     halo lines hit the same per-XCD L2 (FETCH 98MB -> ~80MB expected)
//   - __launch_bounds__(256,8) keeps VGPR <= 64 (occupancy cliff at 64)

#define TILE   64
#define HALO   7
#define LHX    8            // left halo (8 for float4 alignment)
#define NCOL   80           // staged cols: c0-8 .. c0+71
#define NROW   78           // staged rows: r0-7 .. r0+70
#define PSTR   83           // odd; 19 mod 32 -> conflict-free pixel/col patterns
#define PROWSA 81           // rows 0..78 used + 2 slack (safe predicated reads)
#define HH     4096
#define WW     4096

__global__ __launch_bounds__(256, 8) void meanconv_kernel(
    const float* __restrict__ x, const float* __restrict__ mask,
    float* __restrict__ out)
{
    __shared__ float P[PROWSA * PSTR];   // 81*83*4 = 26892 B -> 6 blocks/CU
    const int tid = threadIdx.x;

    // XCD swizzle: consecutive dispatch ids round-robin XCDs; give XCD k the
    // contiguous strip of tiles [512k, 512k+512) (8 full tile-rows).
    const int lid  = blockIdx.x;
    const int tile = ((lid & 7) << 9) | (lid >> 3);
    const int c0   = (tile & 63) * TILE;
    const int r0   = (tile >> 6) * TILE;

    // ---- prefetch mask for this thread's 8x2 output pixels (issued NOW,
    //      consumed after 2 barriers -> latency fully hidden) ----
    const int g  = tid & 7;              // column group (8 groups of 8 px)
    const int ty = tid >> 3;             // 0..31
    const int B0 = 8 * g;
    const size_t mrow0 = (size_t)(r0 + ty) * WW + c0 + B0;
    const size_t mrow1 = (size_t)(r0 + ty + 32) * WW + c0 + B0;
    float4 mk[4];
    mk[0] = *(const float4*)&mask[mrow0];
    mk[1] = *(const float4*)&mask[mrow0 + 4];
    mk[2] = *(const float4*)&mask[mrow1];
    mk[3] = *(const float4*)&mask[mrow1 + 4];

    // zero row 0 (cols 0..80); rows 1..78 written below, no race
    if (tid < 81) P[tid] = 0.0f;

    const bool xint = (c0 >= LHX) && (c0 - LHX + NCOL <= WW);

    // ---- phase 1: fused global stage + row-wise inclusive prefix ----
    for (int idx = tid; idx < NROW * 4; idx += 256) {
        const int lr  = idx >> 2;        // staged row 0..77
        const int s   = idx & 3;         // 20-col segment within the row
        const int gr  = min(max(r0 + lr - HALO, 0), HH - 1);
        const int gc0 = c0 - LHX + 20 * s;
        float v[20];
        if (xint) {
            const float* src = &x[(size_t)gr * WW + gc0];
            #pragma unroll
            for (int q = 0; q < 5; ++q) {
                const float4 t = *(const float4*)(src + 4 * q);
                v[4*q+0] = t.x; v[4*q+1] = t.y; v[4*q+2] = t.z; v[4*q+3] = t.w;
            }
        } else {
            #pragma unroll
            for (int i = 0; i < 20; ++i) {
                const int gc = min(max(gc0 + i, 0), WW - 1);
                v[i] = x[(size_t)gr * WW + gc];
            }
        }
        #pragma unroll
        for (int i = 1; i < 20; ++i) v[i] += v[i - 1];
        // 4-lane (one row) exclusive prefix of segment totals
        const float tot = v[19];
        float sum = tot;
        float u = __shfl_up(sum, 1, 4); if (s >= 1) sum += u;
        u       = __shfl_up(sum, 2, 4); if (s >= 2) sum += u;
        const float off = sum - tot;
        float* dst = &P[(lr + 1) * PSTR + 1 + 20 * s];
        #pragma unroll
        for (int i = 0; i < 20; ++i) dst[i] = v[i] + off;
    }
    __syncthreads();

    // ---- phase 2: column-wise inclusive prefix over rows 1..78 ----
    for (int idx = tid; idx < 80 * 4; idx += 256) {
        const int c  = (idx >> 2) + 1;   // col 1..80
        const int s  = idx & 3;          // row segment (20,20,20,18)
        const int rs = 1 + 20 * s;
        float v[20];
        float run = 0.0f;
        #pragma unroll
        for (int i = 0; i < 20; ++i) {
            const int r = rs + i;
            float t = P[r * PSTR + c];   // rows 79,80 are in-bounds slack
            t = (r < 79) ? t : 0.0f;     // zero out slack garbage
            run += t; v[i] = run;
        }
        const float tot = run;
        float sum = tot;
        float u = __shfl_up(sum, 1, 4); if (s >= 1) sum += u;
        u       = __shfl_up(sum, 2, 4); if (s >= 2) sum += u;
        const float off = sum - tot;
        #pragma unroll
        for (int i = 0; i < 20; ++i) {
            const int r = rs + i;
            if (r < 79) P[r * PSTR + c] = v[i] + off;
        }
    }
    __syncthreads();
    // P[a][b] = sum of staged[row < a][col < b].

    // ---- phase 3: 8 consecutive-x pixels per thread, 2 row-blocks ----
    #pragma unroll
    for (int j = 0; j < 2; ++j) {
        const int rr = ty + 32 * j;      // tile row
        const int A  = rr + HALO;        // staged row of the pixel
        float a[8] = {0.f,0.f,0.f,0.f,0.f,0.f,0.f,0.f};
        #pragma unroll
        for (int p = 1; p <= 7; ++p) {
            const int   k = 2 * p + 1;
            const float w = 1.0f / (7.0f * (float)(k * k));
            const float* rT = &P[(A - p) * PSTR];
            const float* rB = &P[(A + p + 1) * PSTR];
            const int cl = B0 + LHX - p;
            const int cr = cl + 2 * p + 1;
            #pragma unroll
            for (int i = 0; i < 8; ++i) {
                a[i] += w * (rB[cr + i] - rT[cr + i] - rB[cl + i] + rT[cl + i]);
            }
        }
        const int gr = r0 + rr, gc = c0 + B0;
        const float4 m0 = mk[2 * j];
        const float4 m1 = mk[2 * j + 1];
        float4 o0, o1;
        o0.x = a[0] * m0.x; o0.y = a[1] * m0.y; o0.z = a[2] * m0.z; o0.w = a[3] * m0.w;
        o1.x = a[4] * m1.x; o1.y = a[5] * m1.y; o1.z = a[6] * m1.z; o1.w = a[7] * m1.w;
        *(float4*)&out[(size_t)gr * WW + gc]     = o0;
        *(float4*)&out[(size_t)gr * WW + gc + 4] = o1;
    }
}

extern "C" void kernel_launch(void* const* d_in, const int* in_sizes, int n_in,
                              void* d_out, int out_size, void* d_ws, size_t ws_size,
                              hipStream_t stream) {
    const float* x    = (const float*)d_in[0];
    const float* mask = (const float*)d_in[1];
    float*       out  = (float*)d_out;
    meanconv_kernel<<<dim3(64 * 64), 256, 0, stream>>>(x, mask, out);
}

// Round 6
// 204.483 us; speedup vs baseline: 1.0127x; 1.0127x over previous
//
#include <hip/hip_runtime.h>

// MeanConv: out = mask * (1/7) * sum_{k in 3,5,..,15} boxmean_k(x), edge padding.
// Per-tile 2D integral image in LDS; each box sum = 4-corner difference.
// Round-6: all LDS traffic b128-aligned on stride-84 layout (bank-uniform,
// audited: every access pattern is exactly 8 lanes per 4-bank group = the
// b128 data floor, or 2 lanes/bank for b32 column walks = free).
//   - inclusive row prefix, no zero column (LHX=8 keeps left corner >= 0)
//   - phase-3 reads one aligned f4 window per (p,row); offsets unroll-const
//   - XCD swizzle kept (FETCH at ideal 66 MB); mask prefetch reverted
//     (round 5: +24 VGPR crossed the 64 cliff, occupancy 42->28%)

#define TILE   64
#define HALO   7
#define LHX    8            // left halo (8 for float4 alignment)
#define NCOL   80           // staged cols: c0-8 .. c0+71  (staged col = gcol - c0 + 8)
#define NROW   78           // staged rows: r0-7 .. r0+70
#define PSTR   84           // multiple of 4 -> every row base 16B-aligned
#define PROWS  79           // rows 0..78; row 0 is the zero row
#define HH     4096
#define WW     4096

__global__ __launch_bounds__(256, 6) void meanconv_kernel(
    const float* __restrict__ x, const float* __restrict__ mask,
    float* __restrict__ out)
{
    __shared__ __align__(16) float P[PROWS * PSTR];   // 26544 B -> 6 blocks/CU
    const int tid = threadIdx.x;

    // XCD swizzle: give XCD k a contiguous strip of 8 tile-rows (L2 locality).
    const int lid  = blockIdx.x;
    const int tile = ((lid & 7) << 9) | (lid >> 3);
    const int c0   = (tile & 63) * TILE;
    const int r0   = (tile >> 6) * TILE;

    if (tid < PSTR) P[tid] = 0.0f;   // zero row 0 (incl. pad cols, harmless)

    const bool xint = (c0 >= LHX) && (c0 - LHX + NCOL <= WW);

    // ---- phase 1: stage + INCLUSIVE row prefix; write rows 1..78, b128 ----
    for (int idx = tid; idx < NROW * 4; idx += 256) {
        const int lr  = idx >> 2;        // staged row 0..77
        const int s   = idx & 3;         // 20-col segment
        const int gr  = min(max(r0 + lr - HALO, 0), HH - 1);
        const int gc0 = c0 - LHX + 20 * s;
        float v[20];
        if (xint) {
            const float* src = &x[(size_t)gr * WW + gc0];
            #pragma unroll
            for (int q = 0; q < 5; ++q) {
                const float4 t = *(const float4*)(src + 4 * q);
                v[4*q+0] = t.x; v[4*q+1] = t.y; v[4*q+2] = t.z; v[4*q+3] = t.w;
            }
        } else {
            #pragma unroll
            for (int i = 0; i < 20; ++i) {
                const int gc = min(max(gc0 + i, 0), WW - 1);
                v[i] = x[(size_t)gr * WW + gc];
            }
        }
        #pragma unroll
        for (int i = 1; i < 20; ++i) v[i] += v[i - 1];
        const float tot = v[19];
        float sum = tot;
        float u = __shfl_up(sum, 1, 4); if (s >= 1) sum += u;
        u       = __shfl_up(sum, 2, 4); if (s >= 2) sum += u;
        const float off = sum - tot;
        float* dst = &P[(lr + 1) * PSTR + 20 * s];    // col base 20s: 16B-aligned
        #pragma unroll
        for (int q = 0; q < 5; ++q) {
            float4 t;
            t.x = v[4*q+0] + off; t.y = v[4*q+1] + off;
            t.z = v[4*q+2] + off; t.w = v[4*q+3] + off;
            *(float4*)(dst + 4 * q) = t;
        }
    }
    __syncthreads();

    // ---- phase 2: inclusive column prefix over rows 1..78 (b32, 2/bank) ----
    for (int idx = tid; idx < 80 * 4; idx += 256) {
        const int c  = idx >> 2;         // col 0..79
        const int s  = idx & 3;          // row segment (20,20,20,18)
        const int rs = 1 + 20 * s;
        float v[20];
        float run = 0.0f;
        #pragma unroll
        for (int i = 0; i < 20; ++i) {
            const int r = rs + i;
            float t = 0.0f;
            if (r < PROWS) t = P[r * PSTR + c];   // exec-masked, no OOB
            run += t; v[i] = run;
        }
        const float tot = run;
        float sum = tot;
        float u = __shfl_up(sum, 1, 4); if (s >= 1) sum += u;
        u       = __shfl_up(sum, 2, 4); if (s >= 2) sum += u;
        const float off = sum - tot;
        #pragma unroll
        for (int i = 0; i < 20; ++i) {
            const int r = rs + i;
            if (r < PROWS) P[r * PSTR + c] = v[i] + off;
        }
    }
    __syncthreads();
    // P[a][b] = sum over staged rows < a, staged cols <= b.

    // ---- phase 3: 8 px/thread x 2 row-blocks; aligned f4 window loads ----
    const int g  = tid & 7;              // column group
    const int ty = tid >> 3;             // 0..31
    const int B0 = 8 * g;
    #pragma unroll
    for (int j = 0; j < 2; ++j) {
        const int rr = ty + 32 * j;      // tile row
        const int A  = rr + HALO;        // staged row
        float a[8] = {0.f,0.f,0.f,0.f,0.f,0.f,0.f,0.f};
        #pragma unroll
        for (int p = 1; p <= 7; ++p) {
            const int   k   = 2 * p + 1;
            const float w   = 1.0f / (7.0f * (float)(k * k));
            const int   al  = (7 - p) & ~3;          // 4,4,4,0,0,0,0
            const int   lo  = (7 - p) - al;          // left corner offset in window
            const int   ro  = (8 + p) - al;          // right corner offset
            const int   nf4 = (15 + p - al) / 4 + 1; // 4,4,4,5,6,6,6
            const float4* rT4 = (const float4*)&P[(A - p)     * PSTR + B0 + al];
            const float4* rB4 = (const float4*)&P[(A + p + 1) * PSTR + B0 + al];
            float wT[24], wB[24];
            #pragma unroll
            for (int q = 0; q < nf4; ++q) {
                const float4 t = rT4[q];
                wT[4*q+0] = t.x; wT[4*q+1] = t.y; wT[4*q+2] = t.z; wT[4*q+3] = t.w;
                const float4 b = rB4[q];
                wB[4*q+0] = b.x; wB[4*q+1] = b.y; wB[4*q+2] = b.z; wB[4*q+3] = b.w;
            }
            #pragma unroll
            for (int i = 0; i < 8; ++i) {
                a[i] += w * ((wB[ro + i] - wT[ro + i]) - (wB[lo + i] - wT[lo + i]));
            }
        }
        const int gr = r0 + rr, gc = c0 + B0;
        const float4 m0 = *(const float4*)&mask[(size_t)gr * WW + gc];
        const float4 m1 = *(const float4*)&mask[(size_t)gr * WW + gc + 4];
        float4 o0, o1;
        o0.x = a[0] * m0.x; o0.y = a[1] * m0.y; o0.z = a[2] * m0.z; o0.w = a[3] * m0.w;
        o1.x = a[4] * m1.x; o1.y = a[5] * m1.y; o1.z = a[6] * m1.z; o1.w = a[7] * m1.w;
        *(float4*)&out[(size_t)gr * WW + gc]     = o0;
        *(float4*)&out[(size_t)gr * WW + gc + 4] = o1;
    }
}

extern "C" void kernel_launch(void* const* d_in, const int* in_sizes, int n_in,
                              void* d_out, int out_size, void* d_ws, size_t ws_size,
                              hipStream_t stream) {
    const float* x    = (const float*)d_in[0];
    const float* mask = (const float*)d_in[1];
    float*       out  = (float*)d_out;
    meanconv_kernel<<<dim3(64 * 64), 256, 0, stream>>>(x, mask, out);
}

// Round 7
// 198.987 us; speedup vs baseline: 1.0406x; 1.0276x over previous
//
#include <hip/hip_runtime.h>

// MeanConv: out = mask * (1/7) * sum_{k in 3,5,..,15} boxmean_k(x), edge padding.
// Per-tile 2D integral image in LDS; each box sum = 4-corner difference.
// Round-7:
//  - PSTR 83 (odd): phase-3 read2 pattern is exactly 2 lanes/bank (free, m136).
//    Phase-1 writes are b32 (odd stride forbids b128) — also 2 lanes/bank.
//  - phase 1: 2x40-col segments/row (156 tasks, <=1 per thread, ONE global
//    load round; round 4 made wave 0 do 2 rounds while waves 1-3 idled).
//  - phase 2: 2x39-row segments/col (160 tasks, <=1 per thread), two-pass to
//    keep VGPR < 64.
//  - phase 3: round-4 read2 style (round 6's window arrays spilled to scratch:
//    WRITE_SIZE 65->100 MB). Inclusive col sums: cl = B0+7-p, cr = B0+8+p.
//  - XCD swizzle kept (FETCH at ideal ~66 MB). No mask prefetch (VGPR cliff).

#define TILE   64
#define HALO   7
#define LHX    8            // left halo (8 keeps global f4 loads aligned)
#define NCOL   80           // staged cols: c0-8 .. c0+71
#define NROW   78           // staged rows: r0-7 .. r0+70
#define PSTR   83           // ODD: phase-3 conflict-free; 79*83*4 = 26228 B
#define PROWS  79           // row 0 is the zero row; rows 1..78 = staged 0..77
#define HH     4096
#define WW     4096

__global__ __launch_bounds__(256, 8) void meanconv_kernel(
    const float* __restrict__ x, const float* __restrict__ mask,
    float* __restrict__ out)
{
    __shared__ float P[PROWS * PSTR];   // 26228 B -> 6 blocks/CU
    const int tid = threadIdx.x;

    // XCD swizzle: XCD k gets a contiguous strip of 8 tile-rows (L2 locality).
    const int lid  = blockIdx.x;
    const int tile = ((lid & 7) << 9) | (lid >> 3);
    const int c0   = (tile & 63) * TILE;
    const int r0   = (tile >> 6) * TILE;

    if (tid < PSTR) P[tid] = 0.0f;       // zero row 0

    const bool xint = (c0 >= LHX) && (c0 - LHX + NCOL <= WW);

    // ---- phase 1: stage + inclusive row prefix; 156 tasks, 1 per thread ----
    if (tid < NROW * 2) {
        const int lr  = tid >> 1;        // staged row 0..77
        const int s   = tid & 1;         // 40-col segment
        const int gr  = min(max(r0 + lr - HALO, 0), HH - 1);
        const int gc0 = c0 - LHX + 40 * s;
        float v[40];
        if (xint) {
            const float* src = &x[(size_t)gr * WW + gc0];
            #pragma unroll
            for (int q = 0; q < 10; ++q) {
                const float4 t = *(const float4*)(src + 4 * q);
                v[4*q+0] = t.x; v[4*q+1] = t.y; v[4*q+2] = t.z; v[4*q+3] = t.w;
            }
        } else {
            #pragma unroll
            for (int i = 0; i < 40; ++i) {
                const int gc = min(max(gc0 + i, 0), WW - 1);
                v[i] = x[(size_t)gr * WW + gc];
            }
        }
        #pragma unroll
        for (int i = 1; i < 40; ++i) v[i] += v[i - 1];
        const float tot = v[39];
        const float u   = __shfl_up(tot, 1, 2);    // width 2: pair = one row
        const float off = (s == 1) ? u : 0.0f;
        float* dst = &P[(lr + 1) * PSTR + 40 * s];
        #pragma unroll
        for (int i = 0; i < 40; ++i) dst[i] = v[i] + off;
    }
    __syncthreads();

    // ---- phase 2: inclusive column prefix, 160 tasks, two-pass ----
    if (tid < NCOL * 2) {
        const int c  = tid >> 1;         // col 0..79
        const int s  = tid & 1;          // row segment: rows 1..39 / 40..78
        const int rs = 1 + 39 * s;
        float run = 0.0f;
        #pragma unroll
        for (int i = 0; i < 39; ++i) run += P[(rs + i) * PSTR + c];
        const float u   = __shfl_up(run, 1, 2);
        const float off = (s == 1) ? u : 0.0f;
        float acc = off;
        #pragma unroll
        for (int i = 0; i < 39; ++i) {
            acc += P[(rs + i) * PSTR + c];
            P[(rs + i) * PSTR + c] = acc;
        }
    }
    __syncthreads();
    // P[a][b] = sum over staged rows < a, staged cols <= b.

    // ---- phase 3: 8 consecutive-x pixels per thread, 2 row-blocks ----
    const int g  = tid & 7;              // column group
    const int ty = tid >> 3;             // 0..31
    const int B0 = 8 * g;
    #pragma unroll
    for (int j = 0; j < 2; ++j) {
        const int rr = ty + 32 * j;      // tile row
        const int A  = rr + HALO;        // staged row of the pixel
        float a[8] = {0.f,0.f,0.f,0.f,0.f,0.f,0.f,0.f};
        #pragma unroll
        for (int p = 1; p <= 7; ++p) {
            const int   k = 2 * p + 1;
            const float w = 1.0f / (7.0f * (float)(k * k));
            const float* rT = &P[(A - p) * PSTR];
            const float* rB = &P[(A + p + 1) * PSTR];
            const int cl = B0 + 7 - p;   // inclusive-col left corner
            const int cr = B0 + 8 + p;   // inclusive-col right corner
            #pragma unroll
            for (int i = 0; i < 8; ++i) {
                a[i] += w * ((rB[cr + i] - rT[cr + i]) - (rB[cl + i] - rT[cl + i]));
            }
        }
        const int gr = r0 + rr, gc = c0 + B0;
        const float4 m0 = *(const float4*)&mask[(size_t)gr * WW + gc];
        const float4 m1 = *(const float4*)&mask[(size_t)gr * WW + gc + 4];
        float4 o0, o1;
        o0.x = a[0] * m0.x; o0.y = a[1] * m0.y; o0.z = a[2] * m0.z; o0.w = a[3] * m0.w;
        o1.x = a[4] * m1.x; o1.y = a[5] * m1.y; o1.z = a[6] * m1.z; o1.w = a[7] * m1.w;
        *(float4*)&out[(size_t)gr * WW + gc]     = o0;
        *(float4*)&out[(size_t)gr * WW + gc + 4] = o1;
    }
}

extern "C" void kernel_launch(void* const* d_in, const int* in_sizes, int n_in,
                              void* d_out, int out_size, void* d_ws, size_t ws_size,
                              hipStream_t stream) {
    const float* x    = (const float*)d_in[0];
    const float* mask = (const float*)d_in[1];
    float*       out  = (float*)d_out;
    meanconv_kernel<<<dim3(64 * 64), 256, 0, stream>>>(x, mask, out);
}